// Round 5
// baseline (2354.282 us; speedup 1.0000x reference)
//
#include <hip/hip_runtime.h>

typedef __bf16 v8bf __attribute__((ext_vector_type(8)));
typedef __bf16 v4bf __attribute__((ext_vector_type(4)));
typedef float  v4f  __attribute__((ext_vector_type(4)));

#define MFMA16x16x32 __builtin_amdgcn_mfma_f32_16x16x32_bf16

#define HIDDEN 128
#define NHEADS 8

// ---------------- P1: qbf = bf16(x@Wq+bq), hpre = bf16(x@W1a+b1), xbf = bf16(x) ----------------
__global__ __launch_bounds__(512) void pre_kernel(const float* __restrict__ x,
    const float* __restrict__ Wq, const float* __restrict__ bq,
    const float* __restrict__ W1, const float* __restrict__ b1,
    __bf16* __restrict__ qbf, __bf16* __restrict__ hpre, __bf16* __restrict__ xbf, int N)
{
  __shared__ __bf16 X[32][136];
  const int tid = threadIdx.x;
  const int w = tid >> 6, l = tid & 63, qd = l >> 4, ln = l & 15;
  const int col = w*16 + ln;

  v8bf BQ[4], BH[4];
  #pragma unroll
  for (int kk=0; kk<4; kk++) {
    v8bf f, g;
    #pragma unroll
    for (int j=0;j<8;j++){
      f[j] = (__bf16)Wq[(kk*32 + qd*8 + j)*HIDDEN + col];
      g[j] = (__bf16)W1[(kk*32 + qd*8 + j)*HIDDEN + col];
    }
    BQ[kk] = f; BH[kk] = g;
  }
  const float bqv = bq[col], b1v = b1[col];

  const int s = tid >> 4, c8 = (tid & 15)*8;
  for (int n0 = blockIdx.x*32; n0 < N; n0 += gridDim.x*32) {
    __syncthreads();
    int n = n0 + s;
    v8bf xv;
    if (n < N) {
      const float4* xp = (const float4*)(x + (long)n*HIDDEN + c8);
      float4 a = xp[0], b = xp[1];
      xv[0]=(__bf16)a.x; xv[1]=(__bf16)a.y; xv[2]=(__bf16)a.z; xv[3]=(__bf16)a.w;
      xv[4]=(__bf16)b.x; xv[5]=(__bf16)b.y; xv[6]=(__bf16)b.z; xv[7]=(__bf16)b.w;
      *(v8bf*)(xbf + (long)n*HIDDEN + c8) = xv;
    } else {
      #pragma unroll
      for (int j=0;j<8;j++) xv[j] = (__bf16)0.f;
    }
    *(v8bf*)&X[s][c8] = xv;
    __syncthreads();

    v4f q0={0.f,0.f,0.f,0.f}, q1={0.f,0.f,0.f,0.f};
    v4f h0={0.f,0.f,0.f,0.f}, h1={0.f,0.f,0.f,0.f};
    #pragma unroll
    for (int kk=0;kk<4;kk++) {
      v8bf a0 = *(const v8bf*)&X[ln][kk*32 + qd*8];
      v8bf a1 = *(const v8bf*)&X[16+ln][kk*32 + qd*8];
      q0 = MFMA16x16x32(a0, BQ[kk], q0, 0,0,0);
      q1 = MFMA16x16x32(a1, BQ[kk], q1, 0,0,0);
      h0 = MFMA16x16x32(a0, BH[kk], h0, 0,0,0);
      h1 = MFMA16x16x32(a1, BH[kk], h1, 0,0,0);
    }
    #pragma unroll
    for (int r=0;r<4;r++) {
      int n_o = n0 + qd*4 + r;
      if (n_o < N) {
        qbf [(long)n_o*HIDDEN + col] = (__bf16)(q0[r] + bqv);
        hpre[(long)n_o*HIDDEN + col] = (__bf16)(h0[r] + b1v);
      }
      int n2 = n0 + 16 + qd*4 + r;
      if (n2 < N) {
        qbf [(long)n2*HIDDEN + col] = (__bf16)(q1[r] + bqv);
        hpre[(long)n2*HIDDEN + col] = (__bf16)(h1[r] + b1v);
      }
    }
  }
}

// ---------------- P2: merged mlppre (blocks 0..63) + weight swizzle (blocks 64..79) ----------------
__global__ __launch_bounds__(256) void prep_misc(
    const float* __restrict__ rel, const float* __restrict__ W1,
    const float* __restrict__ Wk, const float* __restrict__ Wv,
    const float* __restrict__ W2,
    __bf16* __restrict__ mlppre, __bf16* __restrict__ relbf,
    __bf16* __restrict__ wswz, __bf16* __restrict__ w2bf)
{
  const int b = blockIdx.x;
  if (b < 64) {
    __shared__ float rrow[128];
    const int j = threadIdx.x;
    if (j < 128) rrow[j] = rel[b*HIDDEN + j];
    __syncthreads();
    if (j < 128) {
      float acc = W1[256*HIDDEN + j];            // w1r (tm row)
      #pragma unroll 4
      for (int k=0;k<128;k++) acc += rrow[k]*W1[(128+k)*HIDDEN + j];
      mlppre[b*HIDDEN + j] = (__bf16)acc;
      relbf [b*HIDDEN + j] = (__bf16)rrow[j];
    }
  } else {
    int f = (b - 64)*256 + threadIdx.x;
    if (f < 128) w2bf[f] = (__bf16)W2[f];
    if (f >= 2*8*4*64) return;
    int lane = f & 63, kk = (f>>6)&3, c = (f>>8)&7, mat = f>>11;
    const float* W = mat ? Wv : Wk;
    int qq = lane>>4, nn = lane&15;
    v8bf o;
    #pragma unroll
    for (int j=0;j<8;j++) o[j] = (__bf16)W[(kk*32 + qq*8 + j)*HIDDEN + c*16 + nn];
    *(v8bf*)(wswz + (long)f*8) = o;
  }
}

// ---------------- binning: hist / scan / scatter(meta-gather) ----------------
__global__ void hist_kernel(const int* __restrict__ dst, int* __restrict__ count, int E)
{
  int e = blockIdx.x*blockDim.x + threadIdx.x;
  if (e < E) atomicAdd(&count[dst[e]], 1);
}

__global__ __launch_bounds__(1024) void scan_kernel(const int* __restrict__ count,
    int* __restrict__ base, int N)
{
  __shared__ int ssum[1024];
  const int t = threadIdx.x;
  const int chunk = (N + 1023) >> 10;
  const int lo = t*chunk, hi = min(lo + chunk, N);
  int s = 0;
  for (int i = lo; i < hi; i++) s += count[i];
  ssum[t] = s;
  __syncthreads();
  #pragma unroll
  for (int ofs = 1; ofs < 1024; ofs <<= 1) {
    int v = (t >= ofs) ? ssum[t - ofs] : 0;
    __syncthreads();
    ssum[t] += v;
    __syncthreads();
  }
  int run = (t == 0) ? 0 : ssum[t-1];
  for (int i = lo; i < hi; i++) { base[i] = run; run += count[i]; }
}

// scatter: bin edges by dst AND pre-gather all per-edge metadata into sorted order.
// meta4[p] = {src, dst, etyp, bits(sigmoid((ts[dst]-etime)/|tc|))}
__global__ void scatter_kernel(const int* __restrict__ src, const int* __restrict__ dst,
    const int* __restrict__ etyp, const float* __restrict__ etime,
    const float* __restrict__ ts, const float* __restrict__ tc,
    const int* __restrict__ base, int* __restrict__ cursor,
    int4* __restrict__ meta4, int E)
{
  int e = blockIdx.x*blockDim.x + threadIdx.x;
  if (e < E) {
    int d = dst[e];
    int p = base[d] + atomicAdd(&cursor[d], 1);
    float invtc = 1.0f / (fabsf(tc[0]) + 1e-9f);
    float dt = (ts[d] - etime[e]) * invtc;
    float tm = 1.0f/(1.0f + __expf(-dt));
    meta4[p] = make_int4(src[e], d, etyp[e], __float_as_int(tm));
  }
}

// ---------------- K2 v5: wave-autonomous fused edge kernel, sorted meta ----------------
__global__ __launch_bounds__(1024, 8) void edge_fused(
    const int4* __restrict__ meta4, const float* __restrict__ b2,
    const __bf16* __restrict__ xbf, const __bf16* __restrict__ hpre,
    const __bf16* __restrict__ qbf, const __bf16* __restrict__ relbf,
    const __bf16* __restrict__ mlppre, const __bf16* __restrict__ w2bf,
    const __bf16* __restrict__ wswz,
    const float* __restrict__ bk, const float* __restrict__ bv,
    float* __restrict__ out, float* __restrict__ denom, int E)
{
  __shared__ __bf16 sWK[8][4][512];   // 32 KB: B-frags [c][kk][lane*8]
  __shared__ __bf16 sWV[8][4][512];   // 32 KB

  const int tid = threadIdx.x;
  const int l = tid & 63, qd = l >> 4, ln = l & 15;

  // init: copy swizzled weights (64 KB), then ONE barrier
  for (int i = tid; i < 2048; i += 1024) {
    ((float4*)sWK)[i] = ((const float4*)wswz)[i];
    ((float4*)sWV)[i] = ((const float4*)wswz)[i + 2048];
  }
  __syncthreads();

  const float b2v = b2[0];
  v8bf w2f[4];
  #pragma unroll
  for (int kk=0;kk<4;kk++) w2f[kk] = *(const v8bf*)(w2bf + kk*32 + qd*8);
  float bkC[8], bvC[8];
  #pragma unroll
  for (int c=0;c<8;c++){ bkC[c] = bk[c*16+ln]; bvC[c] = bv[c*16+ln]; }

  const int nwaves = gridDim.x * 16;
  const int wid = blockIdx.x*16 + (tid >> 6);
  const int ntiles = (E + 31) >> 5;

  for (int t = wid; t < ntiles; t += nwaves) {
    const int e0 = t*32;
    // ---- meta: single coalesced 16B load per lane<32 ----
    int4 mt = make_int4(0, -1, 0, 0);
    if (l < 32 && (e0 + l) < E) mt = meta4[e0 + l];
    const int s_m = mt.x, d_m = mt.y, ty_m = mt.z;
    const float tm_m = __int_as_float(mt.w);

    // ---- segment mask over dst runs (dst-sorted) ----
    int dprev = __shfl(d_m, (l>0)?(l-1):0);
    int flag = (l < 32) && ((l==0) || (d_m != dprev));
    unsigned long long segmask = __ballot(flag);

    // ---- broadcast row meta ----
    int srcR[2], tyR[2]; float tmR[2];
    #pragma unroll
    for (int b=0;b<2;b++){
      srcR[b] = __shfl(s_m,  b*16 + ln);
      tyR[b]  = __shfl(ty_m, b*16 + ln);
      tmR[b]  = __shfl(tm_m, b*16 + ln);
    }
    int dC[2][4];
    #pragma unroll
    for (int b=0;b<2;b++)
      #pragma unroll
      for (int r=0;r<4;r++) dC[b][r] = __shfl(d_m, b*16 + qd*4 + r);

    // ---- per row-block: fused MLP (dw) + message into regs ----
    v8bf msg[2][4];
    #pragma unroll
    for (int b=0;b<2;b++){
      const long srow = (long)srcR[b]*HIDDEN;
      const long trow = (long)tyR[b]*HIDDEN;
      v8bf sv[4], av[4], rv[4], bp[4];
      #pragma unroll
      for (int kk=0;kk<4;kk++){
        int ko = kk*32 + qd*8;
        sv[kk] = *(const v8bf*)(xbf   + srow + ko);
        av[kk] = *(const v8bf*)(hpre  + srow + ko);
        rv[kk] = *(const v8bf*)(relbf + trow + ko);
        bp[kk] = *(const v8bf*)(mlppre+ trow + ko);
      }
      const float tmb = tmR[b];
      float z = 0.f;
      #pragma unroll
      for (int kk=0;kk<4;kk++){
        #pragma unroll
        for (int j=0;j<8;j++){
          float p = (float)av[kk][j] + tmb*(float)bp[kk][j];
          z += fmaxf(p, 0.f) * (float)w2f[kk][j];
        }
      }
      z += __shfl_xor(z, 16);
      z += __shfl_xor(z, 32);
      float dw = 1.0f/(1.0f + __expf(-(z + b2v)));
      float s = tmb * dw;                       // fold tm into message scale
      #pragma unroll
      for (int kk=0;kk<4;kk++){
        v8bf m;
        #pragma unroll
        for (int j=0;j<8;j++) m[j] = (__bf16)((float)sv[kk][j]*(float)rv[kk][j]*s);
        msg[b][kk] = m;
      }
    }

    // ---- per head: k/v MFMA, scores, ee, segment flush ----
    #pragma unroll 1
    for (int c=0;c<8;c++){
      v4f aK0={0.f,0.f,0.f,0.f}, aK1={0.f,0.f,0.f,0.f};
      v4f aV0={0.f,0.f,0.f,0.f}, aV1={0.f,0.f,0.f,0.f};
      #pragma unroll
      for (int kk=0;kk<4;kk++){
        v8bf bk8 = *(const v8bf*)&sWK[c][kk][l*8];
        v8bf bv8 = *(const v8bf*)&sWV[c][kk][l*8];
        aK0 = MFMA16x16x32(msg[0][kk], bk8, aK0, 0,0,0);
        aK1 = MFMA16x16x32(msg[1][kk], bk8, aK1, 0,0,0);
        aV0 = MFMA16x16x32(msg[0][kk], bv8, aV0, 0,0,0);
        aV1 = MFMA16x16x32(msg[1][kk], bv8, aV1, 0,0,0);
      }
      const int colg = c*16 + ln;
      const float bkc = bkC[c], bvc = bvC[c];
      float sc[2][4];
      #pragma unroll
      for (int r=0;r<4;r++){
        int d0 = dC[0][r], d1 = dC[1][r];
        float q0 = (float)qbf[(long)(d0<0?0:d0)*HIDDEN + colg];
        float q1 = (float)qbf[(long)(d1<0?0:d1)*HIDDEN + colg];
        sc[0][r] = (aK0[r] + bkc)*q0;
        sc[1][r] = (aK1[r] + bkc)*q1;
      }
      #pragma unroll
      for (int m=1;m<16;m<<=1){
        #pragma unroll
        for (int b=0;b<2;b++)
          #pragma unroll
          for (int r=0;r<4;r++) sc[b][r] += __shfl_xor(sc[b][r], m);
      }
      float ee[2][4], wv[2][4];
      #pragma unroll
      for (int r=0;r<4;r++){
        float e0_ = (dC[0][r] >= 0) ? __expf(sc[0][r]*0.25f) : 0.f;
        float e1_ = (dC[1][r] >= 0) ? __expf(sc[1][r]*0.25f) : 0.f;
        ee[0][r] = e0_; ee[1][r] = e1_;
        wv[0][r] = e0_*(aV0[r] + bvc);
        wv[1][r] = e1_*(aV1[r] + bvc);
      }
      // segment flush: one atomic per (segment,col) + one per (segment,head)
      unsigned long long mm = segmask;
      while (mm){
        int s0 = __ffsll((long long)mm) - 1;
        mm &= mm - 1;
        int s1 = mm ? (__ffsll((long long)mm) - 1) : 32;
        int dseg = __shfl(d_m, s0);
        if (dseg < 0) continue;
        float acc = 0.f, dn = 0.f;
        #pragma unroll
        for (int b=0;b<2;b++)
          #pragma unroll
          for (int r=0;r<4;r++){
            int row = b*16 + qd*4 + r;
            bool in = (row >= s0) && (row < s1);
            acc += in ? wv[b][r] : 0.f;
            dn  += in ? ee[b][r] : 0.f;
          }
        acc += __shfl_xor(acc, 16); acc += __shfl_xor(acc, 32);
        if (l < 16) atomicAdd(&out[(long)dseg*HIDDEN + colg], acc);
        dn += __shfl_xor(dn, 16); dn += __shfl_xor(dn, 32);
        if (l == 0) atomicAdd(&denom[(long)dseg*NHEADS + c], dn);
      }
    }
  }
}

// ---------------- fallback: f32 q + round-1 atomic edge kernel ----------------
__global__ __launch_bounds__(512) void q_kernel(const float* __restrict__ x,
    const float* __restrict__ Wq, const float* __restrict__ bq,
    float* __restrict__ q, int N)
{
  __shared__ __bf16 X[32][136];
  const int tid = threadIdx.x;
  const int w = tid >> 6, l = tid & 63, qd = l >> 4, ln = l & 15;
  const int col = w*16 + ln;
  v8bf B[4];
  #pragma unroll
  for (int kk=0; kk<4; kk++) {
    v8bf f;
    #pragma unroll
    for (int j=0;j<8;j++) f[j] = (__bf16)Wq[(kk*32 + qd*8 + j)*HIDDEN + col];
    B[kk] = f;
  }
  const float bqv = bq[col];
  const int s = tid >> 4, c8 = (tid & 15)*8;
  for (int n0 = blockIdx.x*32; n0 < N; n0 += gridDim.x*32) {
    __syncthreads();
    int n = n0 + s;
    v8bf xv;
    if (n < N) {
      const float4* xp = (const float4*)(x + (long)n*HIDDEN + c8);
      float4 a = xp[0], b = xp[1];
      xv[0]=(__bf16)a.x; xv[1]=(__bf16)a.y; xv[2]=(__bf16)a.z; xv[3]=(__bf16)a.w;
      xv[4]=(__bf16)b.x; xv[5]=(__bf16)b.y; xv[6]=(__bf16)b.z; xv[7]=(__bf16)b.w;
    } else {
      #pragma unroll
      for (int j=0;j<8;j++) xv[j] = (__bf16)0.f;
    }
    *(v8bf*)&X[s][c8] = xv;
    __syncthreads();
    v4f acc0 = {0.f,0.f,0.f,0.f}, acc1 = {0.f,0.f,0.f,0.f};
    #pragma unroll
    for (int kk=0;kk<4;kk++) {
      v8bf a0 = *(const v8bf*)&X[ln][kk*32 + qd*8];
      v8bf a1 = *(const v8bf*)&X[16+ln][kk*32 + qd*8];
      acc0 = MFMA16x16x32(a0, B[kk], acc0, 0,0,0);
      acc1 = MFMA16x16x32(a1, B[kk], acc1, 0,0,0);
    }
    #pragma unroll
    for (int r=0;r<4;r++) {
      int n_o = n0 + qd*4 + r;
      if (n_o < N) q[(long)n_o*HIDDEN + col] = acc0[r] + bqv;
      int n_o2 = n0 + 16 + qd*4 + r;
      if (n_o2 < N) q[(long)n_o2*HIDDEN + col] = acc1[r] + bqv;
    }
  }
}

__global__ __launch_bounds__(512) void edge_atomic(
    const float* __restrict__ x, const float* __restrict__ ts,
    const int* __restrict__ src, const int* __restrict__ dst,
    const int* __restrict__ etyp, const float* __restrict__ etime,
    const float* __restrict__ rel,
    const float* __restrict__ Wk, const float* __restrict__ bk,
    const float* __restrict__ Wv, const float* __restrict__ bv,
    const float* __restrict__ W1, const float* __restrict__ b1,
    const float* __restrict__ W2, const float* __restrict__ b2,
    const float* __restrict__ tc,
    const float* __restrict__ qws, float* __restrict__ denom,
    float* __restrict__ out, int E)
{
  __shared__ __bf16 A[32][264];
  __shared__ __bf16 A2[32][136];
  __shared__ float sW2[128], sb1[128], sw1r[128], sbk[128], sbv[128];
  __shared__ float stm[32], sdw[32];
  __shared__ int   ssrc[32], sdst[32], styp[32];
  __shared__ float dwpart[8][32];
  const int tid = threadIdx.x;
  const int w = tid >> 6, l = tid & 63, qd = l >> 4, ln = l & 15;
  const int col = w*16 + ln;
  v8bf B1[8], BK[4], BV[4];
  #pragma unroll
  for (int kk=0;kk<8;kk++){ v8bf f;
    #pragma unroll
    for (int j=0;j<8;j++) f[j] = (__bf16)W1[(kk*32+qd*8+j)*HIDDEN + col];
    B1[kk]=f; }
  #pragma unroll
  for (int kk=0;kk<4;kk++){ v8bf f,g;
    #pragma unroll
    for (int j=0;j<8;j++){ f[j] = (__bf16)Wk[(kk*32+qd*8+j)*HIDDEN + col];
                           g[j] = (__bf16)Wv[(kk*32+qd*8+j)*HIDDEN + col]; }
    BK[kk]=f; BV[kk]=g; }
  if (tid < 128) {
    sW2[tid]=W2[tid]; sb1[tid]=b1[tid]; sw1r[tid]=W1[256*HIDDEN+tid];
    sbk[tid]=bk[tid]; sbv[tid]=bv[tid];
  }
  const float b2v = b2[0];
  const float invtc = 1.0f / (fabsf(tc[0]) + 1e-9f);
  const int s = tid >> 4, c8 = (tid & 15)*8;
  const int ntiles = (E + 31) >> 5;
  for (int t = blockIdx.x; t < ntiles; t += gridDim.x) {
    const int e0 = t*32;
    __syncthreads();
    if (tid < 32) {
      int e = e0 + tid;
      if (e < E) {
        int d = dst[e];
        ssrc[tid]=src[e]; sdst[tid]=d; styp[tid]=etyp[e];
        float dt = (ts[d] - etime[e]) * invtc;
        stm[tid] = 1.0f/(1.0f+expf(-dt));
      } else { ssrc[tid]=0; sdst[tid]=0; styp[tid]=0; stm[tid]=0.f; }
    }
    __syncthreads();
    {
      const float tmv = stm[s];
      const float4* xp = (const float4*)(x + (long)ssrc[s]*HIDDEN + c8);
      float4 a = xp[0], b = xp[1];
      const float4* rp = (const float4*)(rel + (long)styp[s]*HIDDEN + c8);
      float4 ra = rp[0], rb = rp[1];
      v8bf sv, rv;
      sv[0]=(__bf16)a.x; sv[1]=(__bf16)a.y; sv[2]=(__bf16)a.z; sv[3]=(__bf16)a.w;
      sv[4]=(__bf16)b.x; sv[5]=(__bf16)b.y; sv[6]=(__bf16)b.z; sv[7]=(__bf16)b.w;
      rv[0]=(__bf16)(ra.x*tmv); rv[1]=(__bf16)(ra.y*tmv);
      rv[2]=(__bf16)(ra.z*tmv); rv[3]=(__bf16)(ra.w*tmv);
      rv[4]=(__bf16)(rb.x*tmv); rv[5]=(__bf16)(rb.y*tmv);
      rv[6]=(__bf16)(rb.z*tmv); rv[7]=(__bf16)(rb.w*tmv);
      *(v8bf*)&A[s][c8] = sv;
      *(v8bf*)&A[s][128 + c8] = rv;
    }
    __syncthreads();
    v4f acc0={0.f,0.f,0.f,0.f}, acc1={0.f,0.f,0.f,0.f};
    #pragma unroll
    for (int kk=0;kk<8;kk++){
      v8bf a0 = *(const v8bf*)&A[ln][kk*32 + qd*8];
      v8bf a1 = *(const v8bf*)&A[16+ln][kk*32 + qd*8];
      acc0 = MFMA16x16x32(a0, B1[kk], acc0, 0,0,0);
      acc1 = MFMA16x16x32(a1, B1[kk], acc1, 0,0,0);
    }
    float part[8];
    {
      const float w1rj = sw1r[col], b1j = sb1[col], w2j = sW2[col];
      #pragma unroll
      for (int r=0;r<4;r++){
        int i0 = qd*4 + r, i1 = 16 + qd*4 + r;
        part[r]   = fmaxf(acc0[r] + stm[i0]*w1rj + b1j, 0.f)*w2j;
        part[4+r] = fmaxf(acc1[r] + stm[i1]*w1rj + b1j, 0.f)*w2j;
      }
    }
    #pragma unroll
    for (int m=1;m<16;m<<=1){
      #pragma unroll
      for (int i=0;i<8;i++) part[i] += __shfl_xor(part[i], m, 16);
    }
    if (ln == 0){
      #pragma unroll
      for (int r=0;r<4;r++){ dwpart[w][qd*4+r]=part[r]; dwpart[w][16+qd*4+r]=part[4+r]; }
    }
    __syncthreads();
    if (tid < 32){
      float z = b2v;
      #pragma unroll
      for (int ww=0;ww<8;ww++) z += dwpart[ww][tid];
      sdw[tid] = 1.0f/(1.0f+expf(-z));
    }
    __syncthreads();
    {
      const float dwv = sdw[s];
      v8bf mv;
      #pragma unroll
      for (int i=0;i<8;i++)
        mv[i] = (__bf16)((float)A[s][c8+i]*(float)A[s][128+c8+i]*dwv);
      *(v8bf*)&A2[s][c8] = mv;
    }
    __syncthreads();
    v4f k0={0.f,0.f,0.f,0.f}, k1={0.f,0.f,0.f,0.f};
    v4f v0={0.f,0.f,0.f,0.f}, v1={0.f,0.f,0.f,0.f};
    #pragma unroll
    for (int kk=0;kk<4;kk++){
      v8bf a0 = *(const v8bf*)&A2[ln][kk*32 + qd*8];
      v8bf a1 = *(const v8bf*)&A2[16+ln][kk*32 + qd*8];
      k0 = MFMA16x16x32(a0, BK[kk], k0, 0,0,0);
      k1 = MFMA16x16x32(a1, BK[kk], k1, 0,0,0);
      v0 = MFMA16x16x32(a0, BV[kk], v0, 0,0,0);
      v1 = MFMA16x16x32(a1, BV[kk], v1, 0,0,0);
    }
    float sc[8];
    const float bkj = sbk[col], bvj = sbv[col];
    #pragma unroll
    for (int r=0;r<4;r++){
      int i0 = qd*4 + r, i1 = 16 + qd*4 + r;
      sc[r]   = (k0[r]+bkj)*qws[(long)sdst[i0]*HIDDEN + col];
      sc[4+r] = (k1[r]+bkj)*qws[(long)sdst[i1]*HIDDEN + col];
    }
    #pragma unroll
    for (int m=1;m<16;m<<=1){
      #pragma unroll
      for (int i=0;i<8;i++) sc[i] += __shfl_xor(sc[i], m, 16);
    }
    float ee[8];
    #pragma unroll
    for (int i=0;i<8;i++) ee[i] = expf(sc[i]*0.25f);
    if (ln == 0){
      #pragma unroll
      for (int r=0;r<4;r++){
        int i0 = qd*4 + r, i1 = 16 + qd*4 + r;
        if (e0+i0 < E) atomicAdd(&denom[(long)sdst[i0]*NHEADS + w], ee[r]);
        if (e0+i1 < E) atomicAdd(&denom[(long)sdst[i1]*NHEADS + w], ee[4+r]);
      }
    }
    #pragma unroll
    for (int r=0;r<4;r++){
      int i0 = qd*4 + r, i1 = 16 + qd*4 + r;
      if (e0+i0 < E) atomicAdd(&out[(long)sdst[i0]*HIDDEN + col], ee[r]*(v0[r]+bvj));
      if (e0+i1 < E) atomicAdd(&out[(long)sdst[i1]*HIDDEN + col], ee[4+r]*(v1[r]+bvj));
    }
  }
}

// ---------------- K3: out /= denom ----------------
__global__ void fin_kernel(float* __restrict__ out, const float* __restrict__ denom, int N)
{
  int idx = blockIdx.x*blockDim.x + threadIdx.x;
  int total = N*32;
  if (idx < total){
    int n = idx >> 5;
    int h = (idx & 31) >> 2;
    float d = denom[n*8 + h];
    float inv = d > 0.f ? 1.0f/d : 0.f;
    float4* p = (float4*)out + idx;
    float4 v = *p;
    v.x*=inv; v.y*=inv; v.z*=inv; v.w*=inv;
    *p = v;
  }
}

static inline size_t align256(size_t v){ return (v + 255) & ~(size_t)255; }

extern "C" void kernel_launch(void* const* d_in, const int* in_sizes, int n_in,
                              void* d_out, int out_size, void* d_ws, size_t ws_size,
                              hipStream_t stream)
{
  const float* x      = (const float*)d_in[0];
  const float* ts     = (const float*)d_in[1];
  const int*   src    = (const int*)d_in[2];
  const int*   dstp   = (const int*)d_in[3];
  const int*   etyp   = (const int*)d_in[4];
  const float* etime  = (const float*)d_in[5];
  const float* rel    = (const float*)d_in[6];
  const float* Wq     = (const float*)d_in[7];
  const float* bq     = (const float*)d_in[8];
  const float* Wk     = (const float*)d_in[9];
  const float* bk     = (const float*)d_in[10];
  const float* Wv     = (const float*)d_in[11];
  const float* bv     = (const float*)d_in[12];
  const float* W1     = (const float*)d_in[13];
  const float* b1     = (const float*)d_in[14];
  const float* W2     = (const float*)d_in[15];
  const float* b2     = (const float*)d_in[16];
  const float* tc     = (const float*)d_in[17];
  float* out = (float*)d_out;

  const int N = in_sizes[0] / HIDDEN;
  const int E = in_sizes[2];

  char* ws = (char*)d_ws;
  size_t off = 0;
  __bf16* qbf    = (__bf16*)(ws + off); off += align256((size_t)N*HIDDEN*2);
  __bf16* hpre   = (__bf16*)(ws + off); off += align256((size_t)N*HIDDEN*2);
  __bf16* xbf    = (__bf16*)(ws + off); off += align256((size_t)N*HIDDEN*2);
  __bf16* relbf  = (__bf16*)(ws + off); off += align256((size_t)64*HIDDEN*2);
  __bf16* mlppre = (__bf16*)(ws + off); off += align256((size_t)64*HIDDEN*2);
  __bf16* w2bf   = (__bf16*)(ws + off); off += align256((size_t)HIDDEN*2);
  __bf16* wswz   = (__bf16*)(ws + off); off += align256((size_t)4096*8*2);
  // zero-span: countp, cursor, denom contiguous -> one memset
  size_t zoff = off;
  int*    countp = (int*)(ws + off);    off += align256((size_t)N*4);
  int*    cursor = (int*)(ws + off);    off += align256((size_t)N*4);
  float*  denom  = (float*)(ws + off);  off += align256((size_t)N*NHEADS*4);
  size_t zlen = off - zoff;
  int4*   meta4  = (int4*)(ws + off);   off += align256((size_t)E*16);
  int*    basep  = (int*)(ws + off);    off += align256((size_t)N*4);
  const size_t needed_fast = off;

  if (ws_size >= needed_fast) {
    hipMemsetAsync(ws + zoff, 0, zlen, stream);
    hipMemsetAsync(out, 0, (size_t)N*HIDDEN*4, stream);

    prep_misc<<<80, 256, 0, stream>>>(rel, W1, Wk, Wv, W2, mlppre, relbf, wswz, w2bf);
    hist_kernel<<<(E + 255)/256, 256, 0, stream>>>(dstp, countp, E);
    scan_kernel<<<1, 1024, 0, stream>>>(countp, basep, N);
    scatter_kernel<<<(E + 255)/256, 256, 0, stream>>>(src, dstp, etyp, etime, ts, tc,
        basep, cursor, meta4, E);
    pre_kernel<<<512, 512, 0, stream>>>(x, Wq, bq, W1, b1, qbf, hpre, xbf, N);

    edge_fused<<<512, 1024, 0, stream>>>(meta4, b2,
        xbf, hpre, qbf, relbf, mlppre, w2bf, wswz, bk, bv, out, denom, E);
    fin_kernel<<<(N*32 + 255)/256, 256, 0, stream>>>(out, denom, N);
  } else {
    // -------- fallback: round-1 atomic path --------
    float* qws    = (float*)ws;
    float* denom2 = (float*)(ws + align256((size_t)N*HIDDEN*4));
    hipMemsetAsync(out,    0, (size_t)N*HIDDEN*4, stream);
    hipMemsetAsync(denom2, 0, (size_t)N*NHEADS*4, stream);
    q_kernel<<<512, 512, 0, stream>>>(x, Wq, bq, qws, N);
    edge_atomic<<<512, 512, 0, stream>>>(x, ts, src, dstp, etyp, etime, rel,
        Wk, bk, Wv, bv, W1, b1, W2, b2, tc, qws, denom2, out, E);
    fin_kernel<<<(N*32 + 255)/256, 256, 0, stream>>>(out, denom2, N);
  }
}

// Round 6
// 660.112 us; speedup vs baseline: 3.5665x; 3.5665x over previous
//
#include <hip/hip_runtime.h>

typedef __bf16 v8bf __attribute__((ext_vector_type(8)));
typedef __bf16 v4bf __attribute__((ext_vector_type(4)));
typedef float  v4f  __attribute__((ext_vector_type(4)));

#define MFMA16x16x32 __builtin_amdgcn_mfma_f32_16x16x32_bf16

#define HIDDEN 128
#define NHEADS 8

// ---------------- P1: qbf = bf16(x@Wq+bq), hpre = bf16(x@W1a+b1), xbf = bf16(x) ----------------
__global__ __launch_bounds__(512) void pre_kernel(const float* __restrict__ x,
    const float* __restrict__ Wq, const float* __restrict__ bq,
    const float* __restrict__ W1, const float* __restrict__ b1,
    __bf16* __restrict__ qbf, __bf16* __restrict__ hpre, __bf16* __restrict__ xbf, int N)
{
  __shared__ __bf16 X[32][136];
  const int tid = threadIdx.x;
  const int w = tid >> 6, l = tid & 63, qd = l >> 4, ln = l & 15;
  const int col = w*16 + ln;

  v8bf BQ[4], BH[4];
  #pragma unroll
  for (int kk=0; kk<4; kk++) {
    v8bf f, g;
    #pragma unroll
    for (int j=0;j<8;j++){
      f[j] = (__bf16)Wq[(kk*32 + qd*8 + j)*HIDDEN + col];
      g[j] = (__bf16)W1[(kk*32 + qd*8 + j)*HIDDEN + col];
    }
    BQ[kk] = f; BH[kk] = g;
  }
  const float bqv = bq[col], b1v = b1[col];

  const int s = tid >> 4, c8 = (tid & 15)*8;
  for (int n0 = blockIdx.x*32; n0 < N; n0 += gridDim.x*32) {
    __syncthreads();
    int n = n0 + s;
    v8bf xv;
    if (n < N) {
      const float4* xp = (const float4*)(x + (long)n*HIDDEN + c8);
      float4 a = xp[0], b = xp[1];
      xv[0]=(__bf16)a.x; xv[1]=(__bf16)a.y; xv[2]=(__bf16)a.z; xv[3]=(__bf16)a.w;
      xv[4]=(__bf16)b.x; xv[5]=(__bf16)b.y; xv[6]=(__bf16)b.z; xv[7]=(__bf16)b.w;
      *(v8bf*)(xbf + (long)n*HIDDEN + c8) = xv;
    } else {
      #pragma unroll
      for (int j=0;j<8;j++) xv[j] = (__bf16)0.f;
    }
    *(v8bf*)&X[s][c8] = xv;
    __syncthreads();

    v4f q0={0.f,0.f,0.f,0.f}, q1={0.f,0.f,0.f,0.f};
    v4f h0={0.f,0.f,0.f,0.f}, h1={0.f,0.f,0.f,0.f};
    #pragma unroll
    for (int kk=0;kk<4;kk++) {
      v8bf a0 = *(const v8bf*)&X[ln][kk*32 + qd*8];
      v8bf a1 = *(const v8bf*)&X[16+ln][kk*32 + qd*8];
      q0 = MFMA16x16x32(a0, BQ[kk], q0, 0,0,0);
      q1 = MFMA16x16x32(a1, BQ[kk], q1, 0,0,0);
      h0 = MFMA16x16x32(a0, BH[kk], h0, 0,0,0);
      h1 = MFMA16x16x32(a1, BH[kk], h1, 0,0,0);
    }
    #pragma unroll
    for (int r=0;r<4;r++) {
      int n_o = n0 + qd*4 + r;
      if (n_o < N) {
        qbf [(long)n_o*HIDDEN + col] = (__bf16)(q0[r] + bqv);
        hpre[(long)n_o*HIDDEN + col] = (__bf16)(h0[r] + b1v);
      }
      int n2 = n0 + 16 + qd*4 + r;
      if (n2 < N) {
        qbf [(long)n2*HIDDEN + col] = (__bf16)(q1[r] + bqv);
        hpre[(long)n2*HIDDEN + col] = (__bf16)(h1[r] + b1v);
      }
    }
  }
}

// ---------------- P2: merged mlppre (blocks 0..63) + weight swizzle (blocks 64..79) ----------------
__global__ __launch_bounds__(256) void prep_misc(
    const float* __restrict__ rel, const float* __restrict__ W1,
    const float* __restrict__ Wk, const float* __restrict__ Wv,
    const float* __restrict__ W2,
    __bf16* __restrict__ mlppre, __bf16* __restrict__ relbf,
    __bf16* __restrict__ wswz, __bf16* __restrict__ w2bf)
{
  const int b = blockIdx.x;
  if (b < 64) {
    __shared__ float rrow[128];
    const int j = threadIdx.x;
    if (j < 128) rrow[j] = rel[b*HIDDEN + j];
    __syncthreads();
    if (j < 128) {
      float acc = W1[256*HIDDEN + j];            // w1r (tm row)
      #pragma unroll 4
      for (int k=0;k<128;k++) acc += rrow[k]*W1[(128+k)*HIDDEN + j];
      mlppre[b*HIDDEN + j] = (__bf16)acc;
      relbf [b*HIDDEN + j] = (__bf16)rrow[j];
    }
  } else {
    int f = (b - 64)*256 + threadIdx.x;
    if (f < 128) w2bf[f] = (__bf16)W2[f];
    if (f >= 2*8*4*64) return;
    int lane = f & 63, kk = (f>>6)&3, c = (f>>8)&7, mat = f>>11;
    const float* W = mat ? Wv : Wk;
    int qq = lane>>4, nn = lane&15;
    v8bf o;
    #pragma unroll
    for (int j=0;j<8;j++) o[j] = (__bf16)W[(kk*32 + qq*8 + j)*HIDDEN + c*16 + nn];
    *(v8bf*)(wswz + (long)f*8) = o;
  }
}

// ---------------- binning: hist / scan / scatter(meta-gather) ----------------
__global__ void hist_kernel(const int* __restrict__ dst, int* __restrict__ count, int E)
{
  int e = blockIdx.x*blockDim.x + threadIdx.x;
  if (e < E) atomicAdd(&count[dst[e]], 1);
}

__global__ __launch_bounds__(1024) void scan_kernel(const int* __restrict__ count,
    int* __restrict__ base, int N)
{
  __shared__ int ssum[1024];
  const int t = threadIdx.x;
  const int chunk = (N + 1023) >> 10;
  const int lo = t*chunk, hi = min(lo + chunk, N);
  int s = 0;
  for (int i = lo; i < hi; i++) s += count[i];
  ssum[t] = s;
  __syncthreads();
  #pragma unroll
  for (int ofs = 1; ofs < 1024; ofs <<= 1) {
    int v = (t >= ofs) ? ssum[t - ofs] : 0;
    __syncthreads();
    ssum[t] += v;
    __syncthreads();
  }
  int run = (t == 0) ? 0 : ssum[t-1];
  for (int i = lo; i < hi; i++) { base[i] = run; run += count[i]; }
}

// scatter: bin edges by dst AND pre-gather all per-edge metadata into sorted order.
// meta4[p] = {src, dst, etyp, bits(sigmoid((ts[dst]-etime)/|tc|))}
__global__ void scatter_kernel(const int* __restrict__ src, const int* __restrict__ dst,
    const int* __restrict__ etyp, const float* __restrict__ etime,
    const float* __restrict__ ts, const float* __restrict__ tc,
    const int* __restrict__ base, int* __restrict__ cursor,
    int4* __restrict__ meta4, int E)
{
  int e = blockIdx.x*blockDim.x + threadIdx.x;
  if (e < E) {
    int d = dst[e];
    int p = base[d] + atomicAdd(&cursor[d], 1);
    float invtc = 1.0f / (fabsf(tc[0]) + 1e-9f);
    float dt = (ts[d] - etime[e]) * invtc;
    float tm = 1.0f/(1.0f + __expf(-dt));
    meta4[p] = make_int4(src[e], d, etyp[e], __float_as_int(tm));
  }
}

// ---------------- K2 v6: wave-autonomous fused edge kernel, sorted meta ----------------
// NOTE: no min-waves arg — launch_bounds(1024,8) in r5 forced VGPR 64->32 and
// spilled everything to scratch (FETCH 0.5->5.2 GB). Natural allocation is 64
// VGPR which already supports 8 waves/EU.
__global__ __launch_bounds__(1024) void edge_fused(
    const int4* __restrict__ meta4, const float* __restrict__ b2,
    const __bf16* __restrict__ xbf, const __bf16* __restrict__ hpre,
    const __bf16* __restrict__ qbf, const __bf16* __restrict__ relbf,
    const __bf16* __restrict__ mlppre, const __bf16* __restrict__ w2bf,
    const __bf16* __restrict__ wswz,
    const float* __restrict__ bk, const float* __restrict__ bv,
    float* __restrict__ out, float* __restrict__ denom, int E)
{
  __shared__ __bf16 sWK[8][4][512];   // 32 KB: B-frags [c][kk][lane*8]
  __shared__ __bf16 sWV[8][4][512];   // 32 KB

  const int tid = threadIdx.x;
  const int l = tid & 63, qd = l >> 4, ln = l & 15;

  // init: copy swizzled weights (64 KB), then ONE barrier
  for (int i = tid; i < 2048; i += 1024) {
    ((float4*)sWK)[i] = ((const float4*)wswz)[i];
    ((float4*)sWV)[i] = ((const float4*)wswz)[i + 2048];
  }
  __syncthreads();

  const float b2v = b2[0];
  v8bf w2f[4];
  #pragma unroll
  for (int kk=0;kk<4;kk++) w2f[kk] = *(const v8bf*)(w2bf + kk*32 + qd*8);
  float bkC[8], bvC[8];
  #pragma unroll
  for (int c=0;c<8;c++){ bkC[c] = bk[c*16+ln]; bvC[c] = bv[c*16+ln]; }

  const int nwaves = gridDim.x * 16;
  const int wid = blockIdx.x*16 + (tid >> 6);
  const int ntiles = (E + 31) >> 5;

  for (int t = wid; t < ntiles; t += nwaves) {
    const int e0 = t*32;
    // ---- meta: single coalesced 16B load per lane<32 ----
    int4 mt = make_int4(0, -1, 0, 0);
    if (l < 32 && (e0 + l) < E) mt = meta4[e0 + l];
    const int s_m = mt.x, d_m = mt.y, ty_m = mt.z;
    const float tm_m = __int_as_float(mt.w);

    // ---- segment mask over dst runs (dst-sorted) ----
    int dprev = __shfl(d_m, (l>0)?(l-1):0);
    int flag = (l < 32) && ((l==0) || (d_m != dprev));
    unsigned long long segmask = __ballot(flag);

    // ---- broadcast row meta ----
    int srcR[2], tyR[2]; float tmR[2];
    #pragma unroll
    for (int b=0;b<2;b++){
      srcR[b] = __shfl(s_m,  b*16 + ln);
      tyR[b]  = __shfl(ty_m, b*16 + ln);
      tmR[b]  = __shfl(tm_m, b*16 + ln);
    }
    int dC[2][4];
    #pragma unroll
    for (int b=0;b<2;b++)
      #pragma unroll
      for (int r=0;r<4;r++) dC[b][r] = __shfl(d_m, b*16 + qd*4 + r);

    // ---- per row-block: fused MLP (dw) + message into regs ----
    v8bf msg[2][4];
    #pragma unroll
    for (int b=0;b<2;b++){
      const long srow = (long)srcR[b]*HIDDEN;
      const long trow = (long)tyR[b]*HIDDEN;
      v8bf sv[4], av[4], rv[4], bp[4];
      #pragma unroll
      for (int kk=0;kk<4;kk++){
        int ko = kk*32 + qd*8;
        sv[kk] = *(const v8bf*)(xbf   + srow + ko);
        av[kk] = *(const v8bf*)(hpre  + srow + ko);
        rv[kk] = *(const v8bf*)(relbf + trow + ko);
        bp[kk] = *(const v8bf*)(mlppre+ trow + ko);
      }
      const float tmb = tmR[b];
      float z = 0.f;
      #pragma unroll
      for (int kk=0;kk<4;kk++){
        #pragma unroll
        for (int j=0;j<8;j++){
          float p = (float)av[kk][j] + tmb*(float)bp[kk][j];
          z += fmaxf(p, 0.f) * (float)w2f[kk][j];
        }
      }
      z += __shfl_xor(z, 16);
      z += __shfl_xor(z, 32);
      float dw = 1.0f/(1.0f + __expf(-(z + b2v)));
      float s = tmb * dw;                       // fold tm into message scale
      #pragma unroll
      for (int kk=0;kk<4;kk++){
        v8bf m;
        #pragma unroll
        for (int j=0;j<8;j++) m[j] = (__bf16)((float)sv[kk][j]*(float)rv[kk][j]*s);
        msg[b][kk] = m;
      }
    }

    // ---- per head: k/v MFMA, scores, ee, segment flush ----
    #pragma unroll 1
    for (int c=0;c<8;c++){
      v4f aK0={0.f,0.f,0.f,0.f}, aK1={0.f,0.f,0.f,0.f};
      v4f aV0={0.f,0.f,0.f,0.f}, aV1={0.f,0.f,0.f,0.f};
      #pragma unroll
      for (int kk=0;kk<4;kk++){
        v8bf bk8 = *(const v8bf*)&sWK[c][kk][l*8];
        v8bf bv8 = *(const v8bf*)&sWV[c][kk][l*8];
        aK0 = MFMA16x16x32(msg[0][kk], bk8, aK0, 0,0,0);
        aK1 = MFMA16x16x32(msg[1][kk], bk8, aK1, 0,0,0);
        aV0 = MFMA16x16x32(msg[0][kk], bv8, aV0, 0,0,0);
        aV1 = MFMA16x16x32(msg[1][kk], bv8, aV1, 0,0,0);
      }
      const int colg = c*16 + ln;
      const float bkc = bkC[c], bvc = bvC[c];
      float sc[2][4];
      #pragma unroll
      for (int r=0;r<4;r++){
        int d0 = dC[0][r], d1 = dC[1][r];
        float q0 = (float)qbf[(long)(d0<0?0:d0)*HIDDEN + colg];
        float q1 = (float)qbf[(long)(d1<0?0:d1)*HIDDEN + colg];
        sc[0][r] = (aK0[r] + bkc)*q0;
        sc[1][r] = (aK1[r] + bkc)*q1;
      }
      #pragma unroll
      for (int m=1;m<16;m<<=1){
        #pragma unroll
        for (int b=0;b<2;b++)
          #pragma unroll
          for (int r=0;r<4;r++) sc[b][r] += __shfl_xor(sc[b][r], m);
      }
      float ee[2][4], wv[2][4];
      #pragma unroll
      for (int r=0;r<4;r++){
        float e0_ = (dC[0][r] >= 0) ? __expf(sc[0][r]*0.25f) : 0.f;
        float e1_ = (dC[1][r] >= 0) ? __expf(sc[1][r]*0.25f) : 0.f;
        ee[0][r] = e0_; ee[1][r] = e1_;
        wv[0][r] = e0_*(aV0[r] + bvc);
        wv[1][r] = e1_*(aV1[r] + bvc);
      }
      // segment flush: one atomic per (segment,col) + one per (segment,head)
      unsigned long long mm = segmask;
      while (mm){
        int s0 = __ffsll((long long)mm) - 1;
        mm &= mm - 1;
        int s1 = mm ? (__ffsll((long long)mm) - 1) : 32;
        int dseg = __shfl(d_m, s0);
        if (dseg < 0) continue;
        float acc = 0.f, dn = 0.f;
        #pragma unroll
        for (int b=0;b<2;b++)
          #pragma unroll
          for (int r=0;r<4;r++){
            int row = b*16 + qd*4 + r;
            bool in = (row >= s0) && (row < s1);
            acc += in ? wv[b][r] : 0.f;
            dn  += in ? ee[b][r] : 0.f;
          }
        acc += __shfl_xor(acc, 16); acc += __shfl_xor(acc, 32);
        if (l < 16) atomicAdd(&out[(long)dseg*HIDDEN + colg], acc);
        dn += __shfl_xor(dn, 16); dn += __shfl_xor(dn, 32);
        if (l == 0) atomicAdd(&denom[(long)dseg*NHEADS + c], dn);
      }
    }
  }
}

// ---------------- fallback: f32 q + round-1 atomic edge kernel ----------------
__global__ __launch_bounds__(512) void q_kernel(const float* __restrict__ x,
    const float* __restrict__ Wq, const float* __restrict__ bq,
    float* __restrict__ q, int N)
{
  __shared__ __bf16 X[32][136];
  const int tid = threadIdx.x;
  const int w = tid >> 6, l = tid & 63, qd = l >> 4, ln = l & 15;
  const int col = w*16 + ln;
  v8bf B[4];
  #pragma unroll
  for (int kk=0; kk<4; kk++) {
    v8bf f;
    #pragma unroll
    for (int j=0;j<8;j++) f[j] = (__bf16)Wq[(kk*32 + qd*8 + j)*HIDDEN + col];
    B[kk] = f;
  }
  const float bqv = bq[col];
  const int s = tid >> 4, c8 = (tid & 15)*8;
  for (int n0 = blockIdx.x*32; n0 < N; n0 += gridDim.x*32) {
    __syncthreads();
    int n = n0 + s;
    v8bf xv;
    if (n < N) {
      const float4* xp = (const float4*)(x + (long)n*HIDDEN + c8);
      float4 a = xp[0], b = xp[1];
      xv[0]=(__bf16)a.x; xv[1]=(__bf16)a.y; xv[2]=(__bf16)a.z; xv[3]=(__bf16)a.w;
      xv[4]=(__bf16)b.x; xv[5]=(__bf16)b.y; xv[6]=(__bf16)b.z; xv[7]=(__bf16)b.w;
    } else {
      #pragma unroll
      for (int j=0;j<8;j++) xv[j] = (__bf16)0.f;
    }
    *(v8bf*)&X[s][c8] = xv;
    __syncthreads();
    v4f acc0 = {0.f,0.f,0.f,0.f}, acc1 = {0.f,0.f,0.f,0.f};
    #pragma unroll
    for (int kk=0;kk<4;kk++) {
      v8bf a0 = *(const v8bf*)&X[ln][kk*32 + qd*8];
      v8bf a1 = *(const v8bf*)&X[16+ln][kk*32 + qd*8];
      acc0 = MFMA16x16x32(a0, B[kk], acc0, 0,0,0);
      acc1 = MFMA16x16x32(a1, B[kk], acc1, 0,0,0);
    }
    #pragma unroll
    for (int r=0;r<4;r++) {
      int n_o = n0 + qd*4 + r;
      if (n_o < N) q[(long)n_o*HIDDEN + col] = acc0[r] + bqv;
      int n_o2 = n0 + 16 + qd*4 + r;
      if (n_o2 < N) q[(long)n_o2*HIDDEN + col] = acc1[r] + bqv;
    }
  }
}

__global__ __launch_bounds__(512) void edge_atomic(
    const float* __restrict__ x, const float* __restrict__ ts,
    const int* __restrict__ src, const int* __restrict__ dst,
    const int* __restrict__ etyp, const float* __restrict__ etime,
    const float* __restrict__ rel,
    const float* __restrict__ Wk, const float* __restrict__ bk,
    const float* __restrict__ Wv, const float* __restrict__ bv,
    const float* __restrict__ W1, const float* __restrict__ b1,
    const float* __restrict__ W2, const float* __restrict__ b2,
    const float* __restrict__ tc,
    const float* __restrict__ qws, float* __restrict__ denom,
    float* __restrict__ out, int E)
{
  __shared__ __bf16 A[32][264];
  __shared__ __bf16 A2[32][136];
  __shared__ float sW2[128], sb1[128], sw1r[128], sbk[128], sbv[128];
  __shared__ float stm[32], sdw[32];
  __shared__ int   ssrc[32], sdst[32], styp[32];
  __shared__ float dwpart[8][32];
  const int tid = threadIdx.x;
  const int w = tid >> 6, l = tid & 63, qd = l >> 4, ln = l & 15;
  const int col = w*16 + ln;
  v8bf B1[8], BK[4], BV[4];
  #pragma unroll
  for (int kk=0;kk<8;kk++){ v8bf f;
    #pragma unroll
    for (int j=0;j<8;j++) f[j] = (__bf16)W1[(kk*32+qd*8+j)*HIDDEN + col];
    B1[kk]=f; }
  #pragma unroll
  for (int kk=0;kk<4;kk++){ v8bf f,g;
    #pragma unroll
    for (int j=0;j<8;j++){ f[j] = (__bf16)Wk[(kk*32+qd*8+j)*HIDDEN + col];
                           g[j] = (__bf16)Wv[(kk*32+qd*8+j)*HIDDEN + col]; }
    BK[kk]=f; BV[kk]=g; }
  if (tid < 128) {
    sW2[tid]=W2[tid]; sb1[tid]=b1[tid]; sw1r[tid]=W1[256*HIDDEN+tid];
    sbk[tid]=bk[tid]; sbv[tid]=bv[tid];
  }
  const float b2v = b2[0];
  const float invtc = 1.0f / (fabsf(tc[0]) + 1e-9f);
  const int s = tid >> 4, c8 = (tid & 15)*8;
  const int ntiles = (E + 31) >> 5;
  for (int t = blockIdx.x; t < ntiles; t += gridDim.x) {
    const int e0 = t*32;
    __syncthreads();
    if (tid < 32) {
      int e = e0 + tid;
      if (e < E) {
        int d = dst[e];
        ssrc[tid]=src[e]; sdst[tid]=d; styp[tid]=etyp[e];
        float dt = (ts[d] - etime[e]) * invtc;
        stm[tid] = 1.0f/(1.0f+expf(-dt));
      } else { ssrc[tid]=0; sdst[tid]=0; styp[tid]=0; stm[tid]=0.f; }
    }
    __syncthreads();
    {
      const float tmv = stm[s];
      const float4* xp = (const float4*)(x + (long)ssrc[s]*HIDDEN + c8);
      float4 a = xp[0], b = xp[1];
      const float4* rp = (const float4*)(rel + (long)styp[s]*HIDDEN + c8);
      float4 ra = rp[0], rb = rp[1];
      v8bf sv, rv;
      sv[0]=(__bf16)a.x; sv[1]=(__bf16)a.y; sv[2]=(__bf16)a.z; sv[3]=(__bf16)a.w;
      sv[4]=(__bf16)b.x; sv[5]=(__bf16)b.y; sv[6]=(__bf16)b.z; sv[7]=(__bf16)b.w;
      rv[0]=(__bf16)(ra.x*tmv); rv[1]=(__bf16)(ra.y*tmv);
      rv[2]=(__bf16)(ra.z*tmv); rv[3]=(__bf16)(ra.w*tmv);
      rv[4]=(__bf16)(rb.x*tmv); rv[5]=(__bf16)(rb.y*tmv);
      rv[6]=(__bf16)(rb.z*tmv); rv[7]=(__bf16)(rb.w*tmv);
      *(v8bf*)&A[s][c8] = sv;
      *(v8bf*)&A[s][128 + c8] = rv;
    }
    __syncthreads();
    v4f acc0={0.f,0.f,0.f,0.f}, acc1={0.f,0.f,0.f,0.f};
    #pragma unroll
    for (int kk=0;kk<8;kk++){
      v8bf a0 = *(const v8bf*)&A[ln][kk*32 + qd*8];
      v8bf a1 = *(const v8bf*)&A[16+ln][kk*32 + qd*8];
      acc0 = MFMA16x16x32(a0, B1[kk], acc0, 0,0,0);
      acc1 = MFMA16x16x32(a1, B1[kk], acc1, 0,0,0);
    }
    float part[8];
    {
      const float w1rj = sw1r[col], b1j = sb1[col], w2j = sW2[col];
      #pragma unroll
      for (int r=0;r<4;r++){
        int i0 = qd*4 + r, i1 = 16 + qd*4 + r;
        part[r]   = fmaxf(acc0[r] + stm[i0]*w1rj + b1j, 0.f)*w2j;
        part[4+r] = fmaxf(acc1[r] + stm[i1]*w1rj + b1j, 0.f)*w2j;
      }
    }
    #pragma unroll
    for (int m=1;m<16;m<<=1){
      #pragma unroll
      for (int i=0;i<8;i++) part[i] += __shfl_xor(part[i], m, 16);
    }
    if (ln == 0){
      #pragma unroll
      for (int r=0;r<4;r++){ dwpart[w][qd*4+r]=part[r]; dwpart[w][16+qd*4+r]=part[4+r]; }
    }
    __syncthreads();
    if (tid < 32){
      float z = b2v;
      #pragma unroll
      for (int ww=0;ww<8;ww++) z += dwpart[ww][tid];
      sdw[tid] = 1.0f/(1.0f+expf(-z));
    }
    __syncthreads();
    {
      const float dwv = sdw[s];
      v8bf mv;
      #pragma unroll
      for (int i=0;i<8;i++)
        mv[i] = (__bf16)((float)A[s][c8+i]*(float)A[s][128+c8+i]*dwv);
      *(v8bf*)&A2[s][c8] = mv;
    }
    __syncthreads();
    v4f k0={0.f,0.f,0.f,0.f}, k1={0.f,0.f,0.f,0.f};
    v4f v0={0.f,0.f,0.f,0.f}, v1={0.f,0.f,0.f,0.f};
    #pragma unroll
    for (int kk=0;kk<4;kk++){
      v8bf a0 = *(const v8bf*)&A2[ln][kk*32 + qd*8];
      v8bf a1 = *(const v8bf*)&A2[16+ln][kk*32 + qd*8];
      k0 = MFMA16x16x32(a0, BK[kk], k0, 0,0,0);
      k1 = MFMA16x16x32(a1, BK[kk], k1, 0,0,0);
      v0 = MFMA16x16x32(a0, BV[kk], v0, 0,0,0);
      v1 = MFMA16x16x32(a1, BV[kk], v1, 0,0,0);
    }
    float sc[8];
    const float bkj = sbk[col], bvj = sbv[col];
    #pragma unroll
    for (int r=0;r<4;r++){
      int i0 = qd*4 + r, i1 = 16 + qd*4 + r;
      sc[r]   = (k0[r]+bkj)*qws[(long)sdst[i0]*HIDDEN + col];
      sc[4+r] = (k1[r]+bkj)*qws[(long)sdst[i1]*HIDDEN + col];
    }
    #pragma unroll
    for (int m=1;m<16;m<<=1){
      #pragma unroll
      for (int i=0;i<8;i++) sc[i] += __shfl_xor(sc[i], m, 16);
    }
    float ee[8];
    #pragma unroll
    for (int i=0;i<8;i++) ee[i] = expf(sc[i]*0.25f);
    if (ln == 0){
      #pragma unroll
      for (int r=0;r<4;r++){
        int i0 = qd*4 + r, i1 = 16 + qd*4 + r;
        if (e0+i0 < E) atomicAdd(&denom[(long)sdst[i0]*NHEADS + w], ee[r]);
        if (e0+i1 < E) atomicAdd(&denom[(long)sdst[i1]*NHEADS + w], ee[4+r]);
      }
    }
    #pragma unroll
    for (int r=0;r<4;r++){
      int i0 = qd*4 + r, i1 = 16 + qd*4 + r;
      if (e0+i0 < E) atomicAdd(&out[(long)sdst[i0]*HIDDEN + col], ee[r]*(v0[r]+bvj));
      if (e0+i1 < E) atomicAdd(&out[(long)sdst[i1]*HIDDEN + col], ee[4+r]*(v1[r]+bvj));
    }
  }
}

// ---------------- K3: out /= denom ----------------
__global__ void fin_kernel(float* __restrict__ out, const float* __restrict__ denom, int N)
{
  int idx = blockIdx.x*blockDim.x + threadIdx.x;
  int total = N*32;
  if (idx < total){
    int n = idx >> 5;
    int h = (idx & 31) >> 2;
    float d = denom[n*8 + h];
    float inv = d > 0.f ? 1.0f/d : 0.f;
    float4* p = (float4*)out + idx;
    float4 v = *p;
    v.x*=inv; v.y*=inv; v.z*=inv; v.w*=inv;
    *p = v;
  }
}

static inline size_t align256(size_t v){ return (v + 255) & ~(size_t)255; }

extern "C" void kernel_launch(void* const* d_in, const int* in_sizes, int n_in,
                              void* d_out, int out_size, void* d_ws, size_t ws_size,
                              hipStream_t stream)
{
  const float* x      = (const float*)d_in[0];
  const float* ts     = (const float*)d_in[1];
  const int*   src    = (const int*)d_in[2];
  const int*   dstp   = (const int*)d_in[3];
  const int*   etyp   = (const int*)d_in[4];
  const float* etime  = (const float*)d_in[5];
  const float* rel    = (const float*)d_in[6];
  const float* Wq     = (const float*)d_in[7];
  const float* bq     = (const float*)d_in[8];
  const float* Wk     = (const float*)d_in[9];
  const float* bk     = (const float*)d_in[10];
  const float* Wv     = (const float*)d_in[11];
  const float* bv     = (const float*)d_in[12];
  const float* W1     = (const float*)d_in[13];
  const float* b1     = (const float*)d_in[14];
  const float* W2     = (const float*)d_in[15];
  const float* b2     = (const float*)d_in[16];
  const float* tc     = (const float*)d_in[17];
  float* out = (float*)d_out;

  const int N = in_sizes[0] / HIDDEN;
  const int E = in_sizes[2];

  char* ws = (char*)d_ws;
  size_t off = 0;
  __bf16* qbf    = (__bf16*)(ws + off); off += align256((size_t)N*HIDDEN*2);
  __bf16* hpre   = (__bf16*)(ws + off); off += align256((size_t)N*HIDDEN*2);
  __bf16* xbf    = (__bf16*)(ws + off); off += align256((size_t)N*HIDDEN*2);
  __bf16* relbf  = (__bf16*)(ws + off); off += align256((size_t)64*HIDDEN*2);
  __bf16* mlppre = (__bf16*)(ws + off); off += align256((size_t)64*HIDDEN*2);
  __bf16* w2bf   = (__bf16*)(ws + off); off += align256((size_t)HIDDEN*2);
  __bf16* wswz   = (__bf16*)(ws + off); off += align256((size_t)4096*8*2);
  // zero-span: countp, cursor, denom contiguous -> one memset
  size_t zoff = off;
  int*    countp = (int*)(ws + off);    off += align256((size_t)N*4);
  int*    cursor = (int*)(ws + off);    off += align256((size_t)N*4);
  float*  denom  = (float*)(ws + off);  off += align256((size_t)N*NHEADS*4);
  size_t zlen = off - zoff;
  int4*   meta4  = (int4*)(ws + off);   off += align256((size_t)E*16);
  int*    basep  = (int*)(ws + off);    off += align256((size_t)N*4);
  const size_t needed_fast = off;

  if (ws_size >= needed_fast) {
    hipMemsetAsync(ws + zoff, 0, zlen, stream);
    hipMemsetAsync(out, 0, (size_t)N*HIDDEN*4, stream);

    prep_misc<<<80, 256, 0, stream>>>(rel, W1, Wk, Wv, W2, mlppre, relbf, wswz, w2bf);
    hist_kernel<<<(E + 255)/256, 256, 0, stream>>>(dstp, countp, E);
    scan_kernel<<<1, 1024, 0, stream>>>(countp, basep, N);
    scatter_kernel<<<(E + 255)/256, 256, 0, stream>>>(src, dstp, etyp, etime, ts, tc,
        basep, cursor, meta4, E);
    pre_kernel<<<512, 512, 0, stream>>>(x, Wq, bq, W1, b1, qbf, hpre, xbf, N);

    edge_fused<<<512, 1024, 0, stream>>>(meta4, b2,
        xbf, hpre, qbf, relbf, mlppre, w2bf, wswz, bk, bv, out, denom, E);
    fin_kernel<<<(N*32 + 255)/256, 256, 0, stream>>>(out, denom, N);
  } else {
    // -------- fallback: round-1 atomic path --------
    float* qws    = (float*)ws;
    float* denom2 = (float*)(ws + align256((size_t)N*HIDDEN*4));
    hipMemsetAsync(out,    0, (size_t)N*HIDDEN*4, stream);
    hipMemsetAsync(denom2, 0, (size_t)N*NHEADS*4, stream);
    q_kernel<<<512, 512, 0, stream>>>(x, Wq, bq, qws, N);
    edge_atomic<<<512, 512, 0, stream>>>(x, ts, src, dstp, etyp, etime, rel,
        Wk, bk, Wv, bv, W1, b1, W2, b2, tc, qws, denom2, out, E);
    fin_kernel<<<(N*32 + 255)/256, 256, 0, stream>>>(out, denom2, N);
  }
}

// Round 7
// 637.411 us; speedup vs baseline: 3.6935x; 1.0356x over previous
//
#include <hip/hip_runtime.h>

typedef __bf16 v8bf __attribute__((ext_vector_type(8)));
typedef __bf16 v4bf __attribute__((ext_vector_type(4)));
typedef float  v4f  __attribute__((ext_vector_type(4)));

#define MFMA16x16x32 __builtin_amdgcn_mfma_f32_16x16x32_bf16

#define HIDDEN 128
#define NHEADS 8

// ---------------- P1: qbf = bf16(x@Wq+bq), hpre = bf16(x@W1a+b1), xbf = bf16(x) ----------------
__global__ __launch_bounds__(512) void pre_kernel(const float* __restrict__ x,
    const float* __restrict__ Wq, const float* __restrict__ bq,
    const float* __restrict__ W1, const float* __restrict__ b1,
    __bf16* __restrict__ qbf, __bf16* __restrict__ hpre, __bf16* __restrict__ xbf, int N)
{
  __shared__ __bf16 X[32][136];
  const int tid = threadIdx.x;
  const int w = tid >> 6, l = tid & 63, qd = l >> 4, ln = l & 15;
  const int col = w*16 + ln;

  v8bf BQ[4], BH[4];
  #pragma unroll
  for (int kk=0; kk<4; kk++) {
    v8bf f, g;
    #pragma unroll
    for (int j=0;j<8;j++){
      f[j] = (__bf16)Wq[(kk*32 + qd*8 + j)*HIDDEN + col];
      g[j] = (__bf16)W1[(kk*32 + qd*8 + j)*HIDDEN + col];
    }
    BQ[kk] = f; BH[kk] = g;
  }
  const float bqv = bq[col], b1v = b1[col];

  const int s = tid >> 4, c8 = (tid & 15)*8;
  for (int n0 = blockIdx.x*32; n0 < N; n0 += gridDim.x*32) {
    __syncthreads();
    int n = n0 + s;
    v8bf xv;
    if (n < N) {
      const float4* xp = (const float4*)(x + (long)n*HIDDEN + c8);
      float4 a = xp[0], b = xp[1];
      xv[0]=(__bf16)a.x; xv[1]=(__bf16)a.y; xv[2]=(__bf16)a.z; xv[3]=(__bf16)a.w;
      xv[4]=(__bf16)b.x; xv[5]=(__bf16)b.y; xv[6]=(__bf16)b.z; xv[7]=(__bf16)b.w;
      *(v8bf*)(xbf + (long)n*HIDDEN + c8) = xv;
    } else {
      #pragma unroll
      for (int j=0;j<8;j++) xv[j] = (__bf16)0.f;
    }
    *(v8bf*)&X[s][c8] = xv;
    __syncthreads();

    v4f q0={0.f,0.f,0.f,0.f}, q1={0.f,0.f,0.f,0.f};
    v4f h0={0.f,0.f,0.f,0.f}, h1={0.f,0.f,0.f,0.f};
    #pragma unroll
    for (int kk=0;kk<4;kk++) {
      v8bf a0 = *(const v8bf*)&X[ln][kk*32 + qd*8];
      v8bf a1 = *(const v8bf*)&X[16+ln][kk*32 + qd*8];
      q0 = MFMA16x16x32(a0, BQ[kk], q0, 0,0,0);
      q1 = MFMA16x16x32(a1, BQ[kk], q1, 0,0,0);
      h0 = MFMA16x16x32(a0, BH[kk], h0, 0,0,0);
      h1 = MFMA16x16x32(a1, BH[kk], h1, 0,0,0);
    }
    #pragma unroll
    for (int r=0;r<4;r++) {
      int n_o = n0 + qd*4 + r;
      if (n_o < N) {
        qbf [(long)n_o*HIDDEN + col] = (__bf16)(q0[r] + bqv);
        hpre[(long)n_o*HIDDEN + col] = (__bf16)(h0[r] + b1v);
      }
      int n2 = n0 + 16 + qd*4 + r;
      if (n2 < N) {
        qbf [(long)n2*HIDDEN + col] = (__bf16)(q1[r] + bqv);
        hpre[(long)n2*HIDDEN + col] = (__bf16)(h1[r] + b1v);
      }
    }
  }
}

// ---------------- P2: merged mlppre (blocks 0..63) + weight swizzle (blocks 64..79) ----------------
__global__ __launch_bounds__(256) void prep_misc(
    const float* __restrict__ rel, const float* __restrict__ W1,
    const float* __restrict__ Wk, const float* __restrict__ Wv,
    const float* __restrict__ W2,
    __bf16* __restrict__ mlppre, __bf16* __restrict__ relbf,
    __bf16* __restrict__ wswz, __bf16* __restrict__ w2bf)
{
  const int b = blockIdx.x;
  if (b < 64) {
    __shared__ float rrow[128];
    const int j = threadIdx.x;
    if (j < 128) rrow[j] = rel[b*HIDDEN + j];
    __syncthreads();
    if (j < 128) {
      float acc = W1[256*HIDDEN + j];            // w1r (tm row)
      #pragma unroll 4
      for (int k=0;k<128;k++) acc += rrow[k]*W1[(128+k)*HIDDEN + j];
      mlppre[b*HIDDEN + j] = (__bf16)acc;
      relbf [b*HIDDEN + j] = (__bf16)rrow[j];
    }
  } else {
    int f = (b - 64)*256 + threadIdx.x;
    if (f < 128) w2bf[f] = (__bf16)W2[f];
    if (f >= 2*8*4*64) return;
    int lane = f & 63, kk = (f>>6)&3, c = (f>>8)&7, mat = f>>11;
    const float* W = mat ? Wv : Wk;
    int qq = lane>>4, nn = lane&15;
    v8bf o;
    #pragma unroll
    for (int j=0;j<8;j++) o[j] = (__bf16)W[(kk*32 + qq*8 + j)*HIDDEN + c*16 + nn];
    *(v8bf*)(wswz + (long)f*8) = o;
  }
}

// ---------------- binning: hist / scan / scatter(meta-gather) ----------------
__global__ void hist_kernel(const int* __restrict__ dst, int* __restrict__ count, int E)
{
  int e = blockIdx.x*blockDim.x + threadIdx.x;
  if (e < E) atomicAdd(&count[dst[e]], 1);
}

__global__ __launch_bounds__(1024) void scan_kernel(const int* __restrict__ count,
    int* __restrict__ base, int N)
{
  __shared__ int ssum[1024];
  const int t = threadIdx.x;
  const int chunk = (N + 1023) >> 10;
  const int lo = t*chunk, hi = min(lo + chunk, N);
  int s = 0;
  for (int i = lo; i < hi; i++) s += count[i];
  ssum[t] = s;
  __syncthreads();
  #pragma unroll
  for (int ofs = 1; ofs < 1024; ofs <<= 1) {
    int v = (t >= ofs) ? ssum[t - ofs] : 0;
    __syncthreads();
    ssum[t] += v;
    __syncthreads();
  }
  int run = (t == 0) ? 0 : ssum[t-1];
  for (int i = lo; i < hi; i++) { base[i] = run; run += count[i]; }
}

// scatter: bin edges by dst AND pre-gather all per-edge metadata into sorted order.
// meta4[p] = {src, dst, etyp, bits(sigmoid((ts[dst]-etime)/|tc|))}
__global__ void scatter_kernel(const int* __restrict__ src, const int* __restrict__ dst,
    const int* __restrict__ etyp, const float* __restrict__ etime,
    const float* __restrict__ ts, const float* __restrict__ tc,
    const int* __restrict__ base, int* __restrict__ cursor,
    int4* __restrict__ meta4, int E)
{
  int e = blockIdx.x*blockDim.x + threadIdx.x;
  if (e < E) {
    int d = dst[e];
    int p = base[d] + atomicAdd(&cursor[d], 1);
    float invtc = 1.0f / (fabsf(tc[0]) + 1e-9f);
    float dt = (ts[d] - etime[e]) * invtc;
    float tm = 1.0f/(1.0f + __expf(-dt));
    meta4[p] = make_int4(src[e], d, etyp[e], __float_as_int(tm));
  }
}

// ---------------- K2 v7: wave-autonomous fused edge kernel, ZERO LDS ----------------
// r6 evidence: 64 KB LDS blocks co-residency (256->512 blocks changed nothing,
// occupancy pinned ~39%). Weights are chip-uniform & L2-hot -> read B-frags per
// head straight from global wswz. 256-thread blocks pack into any free slots.
__global__ __launch_bounds__(256) void edge_fused(
    const int4* __restrict__ meta4, const float* __restrict__ b2,
    const __bf16* __restrict__ xbf, const __bf16* __restrict__ hpre,
    const __bf16* __restrict__ qbf, const __bf16* __restrict__ relbf,
    const __bf16* __restrict__ mlppre, const __bf16* __restrict__ w2bf,
    const __bf16* __restrict__ wswz,
    const float* __restrict__ bk, const float* __restrict__ bv,
    float* __restrict__ out, float* __restrict__ denom, int E)
{
  const int tid = threadIdx.x;
  const int l = tid & 63, qd = l >> 4, ln = l & 15;

  const float b2v = b2[0];
  v8bf w2f[4];
  #pragma unroll
  for (int kk=0;kk<4;kk++) w2f[kk] = *(const v8bf*)(w2bf + kk*32 + qd*8);
  float bkC[8], bvC[8];
  #pragma unroll
  for (int c=0;c<8;c++){ bkC[c] = bk[c*16+ln]; bvC[c] = bv[c*16+ln]; }

  const int nwaves = gridDim.x * 4;
  const int wid = blockIdx.x*4 + (tid >> 6);
  const int ntiles = (E + 31) >> 5;

  for (int t = wid; t < ntiles; t += nwaves) {
    const int e0 = t*32;
    // ---- meta: single coalesced 16B load per lane<32 ----
    int4 mt = make_int4(0, -1, 0, 0);
    if (l < 32 && (e0 + l) < E) mt = meta4[e0 + l];
    const int s_m = mt.x, d_m = mt.y, ty_m = mt.z;
    const float tm_m = __int_as_float(mt.w);

    // ---- segment mask over dst runs (dst-sorted) ----
    int dprev = __shfl(d_m, (l>0)?(l-1):0);
    int flag = (l < 32) && ((l==0) || (d_m != dprev));
    unsigned long long segmask = __ballot(flag);

    // ---- broadcast row meta ----
    int srcR[2], tyR[2]; float tmR[2];
    #pragma unroll
    for (int b=0;b<2;b++){
      srcR[b] = __shfl(s_m,  b*16 + ln);
      tyR[b]  = __shfl(ty_m, b*16 + ln);
      tmR[b]  = __shfl(tm_m, b*16 + ln);
    }
    int dC[2][4];
    #pragma unroll
    for (int b=0;b<2;b++)
      #pragma unroll
      for (int r=0;r<4;r++) dC[b][r] = __shfl(d_m, b*16 + qd*4 + r);

    // ---- per row-block: fused MLP (dw) + message into regs ----
    v8bf msg[2][4];
    #pragma unroll
    for (int b=0;b<2;b++){
      const long srow = (long)srcR[b]*HIDDEN;
      const long trow = (long)tyR[b]*HIDDEN;
      v8bf sv[4], av[4], rv[4], bp[4];
      #pragma unroll
      for (int kk=0;kk<4;kk++){
        int ko = kk*32 + qd*8;
        sv[kk] = *(const v8bf*)(xbf   + srow + ko);
        av[kk] = *(const v8bf*)(hpre  + srow + ko);
        rv[kk] = *(const v8bf*)(relbf + trow + ko);
        bp[kk] = *(const v8bf*)(mlppre+ trow + ko);
      }
      const float tmb = tmR[b];
      float z = 0.f;
      #pragma unroll
      for (int kk=0;kk<4;kk++){
        #pragma unroll
        for (int j=0;j<8;j++){
          float p = (float)av[kk][j] + tmb*(float)bp[kk][j];
          z += fmaxf(p, 0.f) * (float)w2f[kk][j];
        }
      }
      z += __shfl_xor(z, 16);
      z += __shfl_xor(z, 32);
      float dw = 1.0f/(1.0f + __expf(-(z + b2v)));
      float s = tmb * dw;                       // fold tm into message scale
      #pragma unroll
      for (int kk=0;kk<4;kk++){
        v8bf m;
        #pragma unroll
        for (int j=0;j<8;j++) m[j] = (__bf16)((float)sv[kk][j]*(float)rv[kk][j]*s);
        msg[b][kk] = m;
      }
    }

    // ---- per head: q gather + weight frags from global, k/v MFMA, scores, flush ----
    #pragma unroll 1
    for (int c=0;c<8;c++){
      const int colg = c*16 + ln;
      // q gather first: latency overlaps weight loads + MFMA issue
      float qv[2][4];
      #pragma unroll
      for (int r=0;r<4;r++){
        int d0 = dC[0][r], d1 = dC[1][r];
        qv[0][r] = (float)qbf[(long)(d0<0?0:d0)*HIDDEN + colg];
        qv[1][r] = (float)qbf[(long)(d1<0?0:d1)*HIDDEN + colg];
      }
      // B-fragments from global (coalesced 1 KB/inst, L2-hot)
      v8bf bkf[4], bvf[4];
      #pragma unroll
      for (int kk=0;kk<4;kk++)
        bkf[kk] = *(const v8bf*)(wswz + c*2048 + kk*512 + (size_t)l*8);
      #pragma unroll
      for (int kk=0;kk<4;kk++)
        bvf[kk] = *(const v8bf*)(wswz + 16384 + c*2048 + kk*512 + (size_t)l*8);

      v4f aK0={0.f,0.f,0.f,0.f}, aK1={0.f,0.f,0.f,0.f};
      v4f aV0={0.f,0.f,0.f,0.f}, aV1={0.f,0.f,0.f,0.f};
      #pragma unroll
      for (int kk=0;kk<4;kk++){
        aK0 = MFMA16x16x32(msg[0][kk], bkf[kk], aK0, 0,0,0);
        aK1 = MFMA16x16x32(msg[1][kk], bkf[kk], aK1, 0,0,0);
        aV0 = MFMA16x16x32(msg[0][kk], bvf[kk], aV0, 0,0,0);
        aV1 = MFMA16x16x32(msg[1][kk], bvf[kk], aV1, 0,0,0);
      }
      const float bkc = bkC[c], bvc = bvC[c];
      float sc[2][4];
      #pragma unroll
      for (int r=0;r<4;r++){
        sc[0][r] = (aK0[r] + bkc)*qv[0][r];
        sc[1][r] = (aK1[r] + bkc)*qv[1][r];
      }
      #pragma unroll
      for (int m=1;m<16;m<<=1){
        #pragma unroll
        for (int b=0;b<2;b++)
          #pragma unroll
          for (int r=0;r<4;r++) sc[b][r] += __shfl_xor(sc[b][r], m);
      }
      float ee[2][4], wv[2][4];
      #pragma unroll
      for (int r=0;r<4;r++){
        float e0_ = (dC[0][r] >= 0) ? __expf(sc[0][r]*0.25f) : 0.f;
        float e1_ = (dC[1][r] >= 0) ? __expf(sc[1][r]*0.25f) : 0.f;
        ee[0][r] = e0_; ee[1][r] = e1_;
        wv[0][r] = e0_*(aV0[r] + bvc);
        wv[1][r] = e1_*(aV1[r] + bvc);
      }
      // segment flush: one atomic per (segment,col) + one per (segment,head)
      unsigned long long mm = segmask;
      while (mm){
        int s0 = __ffsll((long long)mm) - 1;
        mm &= mm - 1;
        int s1 = mm ? (__ffsll((long long)mm) - 1) : 32;
        int dseg = __shfl(d_m, s0);
        if (dseg < 0) continue;
        float acc = 0.f, dn = 0.f;
        #pragma unroll
        for (int b=0;b<2;b++)
          #pragma unroll
          for (int r=0;r<4;r++){
            int row = b*16 + qd*4 + r;
            bool in = (row >= s0) && (row < s1);
            acc += in ? wv[b][r] : 0.f;
            dn  += in ? ee[b][r] : 0.f;
          }
        acc += __shfl_xor(acc, 16); acc += __shfl_xor(acc, 32);
        if (l < 16) atomicAdd(&out[(long)dseg*HIDDEN + colg], acc);
        dn += __shfl_xor(dn, 16); dn += __shfl_xor(dn, 32);
        if (l == 0) atomicAdd(&denom[(long)dseg*NHEADS + c], dn);
      }
    }
  }
}

// ---------------- fallback: f32 q + round-1 atomic edge kernel ----------------
__global__ __launch_bounds__(512) void q_kernel(const float* __restrict__ x,
    const float* __restrict__ Wq, const float* __restrict__ bq,
    float* __restrict__ q, int N)
{
  __shared__ __bf16 X[32][136];
  const int tid = threadIdx.x;
  const int w = tid >> 6, l = tid & 63, qd = l >> 4, ln = l & 15;
  const int col = w*16 + ln;
  v8bf B[4];
  #pragma unroll
  for (int kk=0; kk<4; kk++) {
    v8bf f;
    #pragma unroll
    for (int j=0;j<8;j++) f[j] = (__bf16)Wq[(kk*32 + qd*8 + j)*HIDDEN + col];
    B[kk] = f;
  }
  const float bqv = bq[col];
  const int s = tid >> 4, c8 = (tid & 15)*8;
  for (int n0 = blockIdx.x*32; n0 < N; n0 += gridDim.x*32) {
    __syncthreads();
    int n = n0 + s;
    v8bf xv;
    if (n < N) {
      const float4* xp = (const float4*)(x + (long)n*HIDDEN + c8);
      float4 a = xp[0], b = xp[1];
      xv[0]=(__bf16)a.x; xv[1]=(__bf16)a.y; xv[2]=(__bf16)a.z; xv[3]=(__bf16)a.w;
      xv[4]=(__bf16)b.x; xv[5]=(__bf16)b.y; xv[6]=(__bf16)b.z; xv[7]=(__bf16)b.w;
    } else {
      #pragma unroll
      for (int j=0;j<8;j++) xv[j] = (__bf16)0.f;
    }
    *(v8bf*)&X[s][c8] = xv;
    __syncthreads();
    v4f acc0 = {0.f,0.f,0.f,0.f}, acc1 = {0.f,0.f,0.f,0.f};
    #pragma unroll
    for (int kk=0;kk<4;kk++) {
      v8bf a0 = *(const v8bf*)&X[ln][kk*32 + qd*8];
      v8bf a1 = *(const v8bf*)&X[16+ln][kk*32 + qd*8];
      acc0 = MFMA16x16x32(a0, B[kk], acc0, 0,0,0);
      acc1 = MFMA16x16x32(a1, B[kk], acc1, 0,0,0);
    }
    #pragma unroll
    for (int r=0;r<4;r++) {
      int n_o = n0 + qd*4 + r;
      if (n_o < N) q[(long)n_o*HIDDEN + col] = acc0[r] + bqv;
      int n_o2 = n0 + 16 + qd*4 + r;
      if (n_o2 < N) q[(long)n_o2*HIDDEN + col] = acc1[r] + bqv;
    }
  }
}

__global__ __launch_bounds__(512) void edge_atomic(
    const float* __restrict__ x, const float* __restrict__ ts,
    const int* __restrict__ src, const int* __restrict__ dst,
    const int* __restrict__ etyp, const float* __restrict__ etime,
    const float* __restrict__ rel,
    const float* __restrict__ Wk, const float* __restrict__ bk,
    const float* __restrict__ Wv, const float* __restrict__ bv,
    const float* __restrict__ W1, const float* __restrict__ b1,
    const float* __restrict__ W2, const float* __restrict__ b2,
    const float* __restrict__ tc,
    const float* __restrict__ qws, float* __restrict__ denom,
    float* __restrict__ out, int E)
{
  __shared__ __bf16 A[32][264];
  __shared__ __bf16 A2[32][136];
  __shared__ float sW2[128], sb1[128], sw1r[128], sbk[128], sbv[128];
  __shared__ float stm[32], sdw[32];
  __shared__ int   ssrc[32], sdst[32], styp[32];
  __shared__ float dwpart[8][32];
  const int tid = threadIdx.x;
  const int w = tid >> 6, l = tid & 63, qd = l >> 4, ln = l & 15;
  const int col = w*16 + ln;
  v8bf B1[8], BK[4], BV[4];
  #pragma unroll
  for (int kk=0;kk<8;kk++){ v8bf f;
    #pragma unroll
    for (int j=0;j<8;j++) f[j] = (__bf16)W1[(kk*32+qd*8+j)*HIDDEN + col];
    B1[kk]=f; }
  #pragma unroll
  for (int kk=0;kk<4;kk++){ v8bf f,g;
    #pragma unroll
    for (int j=0;j<8;j++){ f[j] = (__bf16)Wk[(kk*32+qd*8+j)*HIDDEN + col];
                           g[j] = (__bf16)Wv[(kk*32+qd*8+j)*HIDDEN + col]; }
    BK[kk]=f; BV[kk]=g; }
  if (tid < 128) {
    sW2[tid]=W2[tid]; sb1[tid]=b1[tid]; sw1r[tid]=W1[256*HIDDEN+tid];
    sbk[tid]=bk[tid]; sbv[tid]=bv[tid];
  }
  const float b2v = b2[0];
  const float invtc = 1.0f / (fabsf(tc[0]) + 1e-9f);
  const int s = tid >> 4, c8 = (tid & 15)*8;
  const int ntiles = (E + 31) >> 5;
  for (int t = blockIdx.x; t < ntiles; t += gridDim.x) {
    const int e0 = t*32;
    __syncthreads();
    if (tid < 32) {
      int e = e0 + tid;
      if (e < E) {
        int d = dst[e];
        ssrc[tid]=src[e]; sdst[tid]=d; styp[tid]=etyp[e];
        float dt = (ts[d] - etime[e]) * invtc;
        stm[tid] = 1.0f/(1.0f+expf(-dt));
      } else { ssrc[tid]=0; sdst[tid]=0; styp[tid]=0; stm[tid]=0.f; }
    }
    __syncthreads();
    {
      const float tmv = stm[s];
      const float4* xp = (const float4*)(x + (long)ssrc[s]*HIDDEN + c8);
      float4 a = xp[0], b = xp[1];
      const float4* rp = (const float4*)(rel + (long)styp[s]*HIDDEN + c8);
      float4 ra = rp[0], rb = rp[1];
      v8bf sv, rv;
      sv[0]=(__bf16)a.x; sv[1]=(__bf16)a.y; sv[2]=(__bf16)a.z; sv[3]=(__bf16)a.w;
      sv[4]=(__bf16)b.x; sv[5]=(__bf16)b.y; sv[6]=(__bf16)b.z; sv[7]=(__bf16)b.w;
      rv[0]=(__bf16)(ra.x*tmv); rv[1]=(__bf16)(ra.y*tmv);
      rv[2]=(__bf16)(ra.z*tmv); rv[3]=(__bf16)(ra.w*tmv);
      rv[4]=(__bf16)(rb.x*tmv); rv[5]=(__bf16)(rb.y*tmv);
      rv[6]=(__bf16)(rb.z*tmv); rv[7]=(__bf16)(rb.w*tmv);
      *(v8bf*)&A[s][c8] = sv;
      *(v8bf*)&A[s][128 + c8] = rv;
    }
    __syncthreads();
    v4f acc0={0.f,0.f,0.f,0.f}, acc1={0.f,0.f,0.f,0.f};
    #pragma unroll
    for (int kk=0;kk<8;kk++){
      v8bf a0 = *(const v8bf*)&A[ln][kk*32 + qd*8];
      v8bf a1 = *(const v8bf*)&A[16+ln][kk*32 + qd*8];
      acc0 = MFMA16x16x32(a0, B1[kk], acc0, 0,0,0);
      acc1 = MFMA16x16x32(a1, B1[kk], acc1, 0,0,0);
    }
    float part[8];
    {
      const float w1rj = sw1r[col], b1j = sb1[col], w2j = sW2[col];
      #pragma unroll
      for (int r=0;r<4;r++){
        int i0 = qd*4 + r, i1 = 16 + qd*4 + r;
        part[r]   = fmaxf(acc0[r] + stm[i0]*w1rj + b1j, 0.f)*w2j;
        part[4+r] = fmaxf(acc1[r] + stm[i1]*w1rj + b1j, 0.f)*w2j;
      }
    }
    #pragma unroll
    for (int m=1;m<16;m<<=1){
      #pragma unroll
      for (int i=0;i<8;i++) part[i] += __shfl_xor(part[i], m, 16);
    }
    if (ln == 0){
      #pragma unroll
      for (int r=0;r<4;r++){ dwpart[w][qd*4+r]=part[r]; dwpart[w][16+qd*4+r]=part[4+r]; }
    }
    __syncthreads();
    if (tid < 32){
      float z = b2v;
      #pragma unroll
      for (int ww=0;ww<8;ww++) z += dwpart[ww][tid];
      sdw[tid] = 1.0f/(1.0f+expf(-z));
    }
    __syncthreads();
    {
      const float dwv = sdw[s];
      v8bf mv;
      #pragma unroll
      for (int i=0;i<8;i++)
        mv[i] = (__bf16)((float)A[s][c8+i]*(float)A[s][128+c8+i]*dwv);
      *(v8bf*)&A2[s][c8] = mv;
    }
    __syncthreads();
    v4f k0={0.f,0.f,0.f,0.f}, k1={0.f,0.f,0.f,0.f};
    v4f v0={0.f,0.f,0.f,0.f}, v1={0.f,0.f,0.f,0.f};
    #pragma unroll
    for (int kk=0;kk<4;kk++){
      v8bf a0 = *(const v8bf*)&A2[ln][kk*32 + qd*8];
      v8bf a1 = *(const v8bf*)&A2[16+ln][kk*32 + qd*8];
      k0 = MFMA16x16x32(a0, BK[kk], k0, 0,0,0);
      k1 = MFMA16x16x32(a1, BK[kk], k1, 0,0,0);
      v0 = MFMA16x16x32(a0, BV[kk], v0, 0,0,0);
      v1 = MFMA16x16x32(a1, BV[kk], v1, 0,0,0);
    }
    float sc[8];
    const float bkj = sbk[col], bvj = sbv[col];
    #pragma unroll
    for (int r=0;r<4;r++){
      int i0 = qd*4 + r, i1 = 16 + qd*4 + r;
      sc[r]   = (k0[r]+bkj)*qws[(long)sdst[i0]*HIDDEN + col];
      sc[4+r] = (k1[r]+bkj)*qws[(long)sdst[i1]*HIDDEN + col];
    }
    #pragma unroll
    for (int m=1;m<16;m<<=1){
      #pragma unroll
      for (int i=0;i<8;i++) sc[i] += __shfl_xor(sc[i], m, 16);
    }
    float ee[8];
    #pragma unroll
    for (int i=0;i<8;i++) ee[i] = expf(sc[i]*0.25f);
    if (ln == 0){
      #pragma unroll
      for (int r=0;r<4;r++){
        int i0 = qd*4 + r, i1 = 16 + qd*4 + r;
        if (e0+i0 < E) atomicAdd(&denom[(long)sdst[i0]*NHEADS + w], ee[r]);
        if (e0+i1 < E) atomicAdd(&denom[(long)sdst[i1]*NHEADS + w], ee[4+r]);
      }
    }
    #pragma unroll
    for (int r=0;r<4;r++){
      int i0 = qd*4 + r, i1 = 16 + qd*4 + r;
      if (e0+i0 < E) atomicAdd(&out[(long)sdst[i0]*HIDDEN + col], ee[r]*(v0[r]+bvj));
      if (e0+i1 < E) atomicAdd(&out[(long)sdst[i1]*HIDDEN + col], ee[4+r]*(v1[r]+bvj));
    }
  }
}

// ---------------- K3: out /= denom ----------------
__global__ void fin_kernel(float* __restrict__ out, const float* __restrict__ denom, int N)
{
  int idx = blockIdx.x*blockDim.x + threadIdx.x;
  int total = N*32;
  if (idx < total){
    int n = idx >> 5;
    int h = (idx & 31) >> 2;
    float d = denom[n*8 + h];
    float inv = d > 0.f ? 1.0f/d : 0.f;
    float4* p = (float4*)out + idx;
    float4 v = *p;
    v.x*=inv; v.y*=inv; v.z*=inv; v.w*=inv;
    *p = v;
  }
}

static inline size_t align256(size_t v){ return (v + 255) & ~(size_t)255; }

extern "C" void kernel_launch(void* const* d_in, const int* in_sizes, int n_in,
                              void* d_out, int out_size, void* d_ws, size_t ws_size,
                              hipStream_t stream)
{
  const float* x      = (const float*)d_in[0];
  const float* ts     = (const float*)d_in[1];
  const int*   src    = (const int*)d_in[2];
  const int*   dstp   = (const int*)d_in[3];
  const int*   etyp   = (const int*)d_in[4];
  const float* etime  = (const float*)d_in[5];
  const float* rel    = (const float*)d_in[6];
  const float* Wq     = (const float*)d_in[7];
  const float* bq     = (const float*)d_in[8];
  const float* Wk     = (const float*)d_in[9];
  const float* bk     = (const float*)d_in[10];
  const float* Wv     = (const float*)d_in[11];
  const float* bv     = (const float*)d_in[12];
  const float* W1     = (const float*)d_in[13];
  const float* b1     = (const float*)d_in[14];
  const float* W2     = (const float*)d_in[15];
  const float* b2     = (const float*)d_in[16];
  const float* tc     = (const float*)d_in[17];
  float* out = (float*)d_out;

  const int N = in_sizes[0] / HIDDEN;
  const int E = in_sizes[2];

  char* ws = (char*)d_ws;
  size_t off = 0;
  __bf16* qbf    = (__bf16*)(ws + off); off += align256((size_t)N*HIDDEN*2);
  __bf16* hpre   = (__bf16*)(ws + off); off += align256((size_t)N*HIDDEN*2);
  __bf16* xbf    = (__bf16*)(ws + off); off += align256((size_t)N*HIDDEN*2);
  __bf16* relbf  = (__bf16*)(ws + off); off += align256((size_t)64*HIDDEN*2);
  __bf16* mlppre = (__bf16*)(ws + off); off += align256((size_t)64*HIDDEN*2);
  __bf16* w2bf   = (__bf16*)(ws + off); off += align256((size_t)HIDDEN*2);
  __bf16* wswz   = (__bf16*)(ws + off); off += align256((size_t)4096*8*2);
  // zero-span: countp, cursor, denom contiguous -> one memset
  size_t zoff = off;
  int*    countp = (int*)(ws + off);    off += align256((size_t)N*4);
  int*    cursor = (int*)(ws + off);    off += align256((size_t)N*4);
  float*  denom  = (float*)(ws + off);  off += align256((size_t)N*NHEADS*4);
  size_t zlen = off - zoff;
  int4*   meta4  = (int4*)(ws + off);   off += align256((size_t)E*16);
  int*    basep  = (int*)(ws + off);    off += align256((size_t)N*4);
  const size_t needed_fast = off;

  if (ws_size >= needed_fast) {
    hipMemsetAsync(ws + zoff, 0, zlen, stream);
    hipMemsetAsync(out, 0, (size_t)N*HIDDEN*4, stream);

    prep_misc<<<80, 256, 0, stream>>>(rel, W1, Wk, Wv, W2, mlppre, relbf, wswz, w2bf);
    hist_kernel<<<(E + 255)/256, 256, 0, stream>>>(dstp, countp, E);
    scan_kernel<<<1, 1024, 0, stream>>>(countp, basep, N);
    scatter_kernel<<<(E + 255)/256, 256, 0, stream>>>(src, dstp, etyp, etime, ts, tc,
        basep, cursor, meta4, E);
    pre_kernel<<<512, 512, 0, stream>>>(x, Wq, bq, W1, b1, qbf, hpre, xbf, N);

    edge_fused<<<3072, 256, 0, stream>>>(meta4, b2,
        xbf, hpre, qbf, relbf, mlppre, w2bf, wswz, bk, bv, out, denom, E);
    fin_kernel<<<(N*32 + 255)/256, 256, 0, stream>>>(out, denom, N);
  } else {
    // -------- fallback: round-1 atomic path --------
    float* qws    = (float*)ws;
    float* denom2 = (float*)(ws + align256((size_t)N*HIDDEN*4));
    hipMemsetAsync(out,    0, (size_t)N*HIDDEN*4, stream);
    hipMemsetAsync(denom2, 0, (size_t)N*NHEADS*4, stream);
    q_kernel<<<512, 512, 0, stream>>>(x, Wq, bq, qws, N);
    edge_atomic<<<512, 512, 0, stream>>>(x, ts, src, dstp, etyp, etime, rel,
        Wk, bk, Wv, bv, W1, b1, W2, b2, tc, qws, denom2, out, E);
    fin_kernel<<<(N*32 + 255)/256, 256, 0, stream>>>(out, denom2, N);
  }
}